// Round 1
// baseline (400.849 us; speedup 1.0000x reference)
//
#include <hip/hip_runtime.h>
#include <hip/hip_bf16.h>

// ---------------- constants ----------------
constexpr int HH   = 180;
constexpr int WW   = 360;
constexpr int CC   = 192;
constexpr int WS   = 6;
constexpr int SHIFT= 3;
constexpr int NH   = 6;
constexpr int MLAT = HH / WS;   // 30
constexpr int MLON = WW / WS;   // 60
constexpr int NWIN = MLAT * MLON; // 1800
constexpr int NTOK = WS * WS;   // 36
constexpr int HD   = CC / NH;   // 32
constexpr long M_TOK = (long)NWIN * NTOK;  // 64800
constexpr long M_PAD = 64896;              // 507 * 128
constexpr float SCALE_F = 0.17677669529663687f; // 32^-0.5

typedef unsigned short ushort_t;
using bf16x8 = __attribute__((ext_vector_type(8))) short;
using f32x4  = __attribute__((ext_vector_type(4))) float;

static __device__ inline float b2f(ushort_t u) {
    union { float f; unsigned int i; } v; v.i = ((unsigned int)u) << 16; return v.f;
}
static __device__ inline ushort_t f2b(float f) {
    union { float f; unsigned int i; } v; v.f = f;
    unsigned int r = v.i + 0x7FFFu + ((v.i >> 16) & 1u);
    return (ushort_t)(r >> 16);
}

// ---------------- weight transpose + bf16 convert ----------------
// out[n*K + k] = bf16(in[k*N + n]); out is (N x K) row-major.
__global__ void transpose_f2b(const float* __restrict__ in, ushort_t* __restrict__ out,
                              int K, int N) {
    int e = blockIdx.x * 256 + threadIdx.x;
    if (e >= K * N) return;
    int n = e / K, k = e - n * K;
    out[e] = f2b(in[(long)k * N + n]);
}

__global__ void zero_bf16(ushort_t* __restrict__ p, int count) {
    int e = blockIdx.x * 256 + threadIdx.x;
    if (e < count) p[e] = 0;
}

// ---------------- LN1 + cyclic shift + window partition -> bf16 ----------------
// one wave per token (4 waves / block)
__global__ __launch_bounds__(256) void ln1_window_kernel(
    const float* __restrict__ x, const float* __restrict__ g, const float* __restrict__ b,
    ushort_t* __restrict__ xw)
{
    long t = (long)blockIdx.x * 4 + (threadIdx.x >> 6);
    int lane = threadIdx.x & 63;
    if (t >= M_PAD) return;
    if (t >= M_TOK) {
        ushort_t* o = xw + t * CC;
        o[lane] = 0; o[lane + 64] = 0; o[lane + 128] = 0;
        return;
    }
    int ti = (int)t;
    int w = ti / NTOK, n = ti - w * NTOK;
    int mlat = w / MLON, mlon = w - mlat * MLON;
    int sh = mlat * WS + n / WS, sw = mlon * WS + (n % WS);
    int hh = sh + SHIFT; if (hh >= HH) hh -= HH;
    int ww = sw + SHIFT; if (ww >= WW) ww -= WW;
    const float* row = x + ((long)hh * WW + ww) * CC;
    float v0 = row[lane], v1 = row[lane + 64], v2 = row[lane + 128];
    float s = v0 + v1 + v2;
    float ss = v0 * v0 + v1 * v1 + v2 * v2;
    #pragma unroll
    for (int o = 32; o > 0; o >>= 1) { s += __shfl_xor(s, o, 64); ss += __shfl_xor(ss, o, 64); }
    float mu = s * (1.0f / CC);
    float var = ss * (1.0f / CC) - mu * mu;
    float rinv = rsqrtf(var + 1e-5f);
    ushort_t* o = xw + t * CC;
    o[lane]       = f2b((v0 - mu) * rinv * g[lane]       + b[lane]);
    o[lane + 64]  = f2b((v1 - mu) * rinv * g[lane + 64]  + b[lane + 64]);
    o[lane + 128] = f2b((v2 - mu) * rinv * g[lane + 128] + b[lane + 128]);
}

// ---------------- LN2 (identity mapping) ----------------
__global__ __launch_bounds__(256) void ln2_kernel(
    const float* __restrict__ xin, const float* __restrict__ g, const float* __restrict__ b,
    ushort_t* __restrict__ h2)
{
    long t = (long)blockIdx.x * 4 + (threadIdx.x >> 6);
    int lane = threadIdx.x & 63;
    if (t >= M_PAD) return;
    if (t >= M_TOK) {
        ushort_t* o = h2 + t * CC;
        o[lane] = 0; o[lane + 64] = 0; o[lane + 128] = 0;
        return;
    }
    const float* row = xin + t * CC;
    float v0 = row[lane], v1 = row[lane + 64], v2 = row[lane + 128];
    float s = v0 + v1 + v2;
    float ss = v0 * v0 + v1 * v1 + v2 * v2;
    #pragma unroll
    for (int o = 32; o > 0; o >>= 1) { s += __shfl_xor(s, o, 64); ss += __shfl_xor(ss, o, 64); }
    float mu = s * (1.0f / CC);
    float var = ss * (1.0f / CC) - mu * mu;
    float rinv = rsqrtf(var + 1e-5f);
    ushort_t* o = h2 + t * CC;
    o[lane]       = f2b((v0 - mu) * rinv * g[lane]       + b[lane]);
    o[lane + 64]  = f2b((v1 - mu) * rinv * g[lane + 64]  + b[lane + 64]);
    o[lane + 128] = f2b((v2 - mu) * rinv * g[lane + 128] + b[lane + 128]);
}

// ---------------- MFMA GEMM: C = A(bf16, M_PAD x K) * Bt^T (Bt: N x K bf16) ----------------
// MODE 0: outb = bf16(acc + bias)                      (QKV)
// MODE 1: outb = bf16(gelu(acc + bias))                (FC1)
// MODE 2: out fp32 scatter: window-reverse + residual  (proj)
// MODE 3: outf[row] += acc + bias                      (FC2)
#define BM 128
#define BN 64
#define BK 32

template<int MODE>
__global__ __launch_bounds__(256) void gemm_bf16(
    const ushort_t* __restrict__ A, const ushort_t* __restrict__ Bt,
    const float* __restrict__ bias,
    ushort_t* __restrict__ outb, float* __restrict__ outf,
    const float* __restrict__ resid,
    int K, int N, long Mguard)
{
    __shared__ __align__(16) ushort_t As[BM][BK];
    __shared__ __align__(16) ushort_t Bs[BN][BK];
    int tid = threadIdx.x;
    int lane = tid & 63;
    int wid = tid >> 6;
    int wm = wid >> 1, wn = wid & 1;
    long bm0 = (long)blockIdx.x * BM;
    int n0 = blockIdx.y * BN;

    f32x4 acc[4][2] = {};

    int nk = K / BK;
    for (int kt = 0; kt < nk; ++kt) {
        int k0 = kt * BK;
        #pragma unroll
        for (int i = 0; i < 2; ++i) {
            int c = tid + 256 * i;
            int row = c >> 2, seg = c & 3;
            *(uint4*)&As[row][seg * 8] =
                *(const uint4*)&A[(bm0 + row) * K + k0 + seg * 8];
        }
        {
            int row = tid >> 2, seg = tid & 3;
            *(uint4*)&Bs[row][seg * 8] =
                *(const uint4*)&Bt[(long)(n0 + row) * K + k0 + seg * 8];
        }
        __syncthreads();
        bf16x8 af[4], bfr[2];
        #pragma unroll
        for (int fm = 0; fm < 4; ++fm)
            af[fm] = *(const bf16x8*)&As[wm * 64 + fm * 16 + (lane & 15)][8 * (lane >> 4)];
        #pragma unroll
        for (int fn = 0; fn < 2; ++fn)
            bfr[fn] = *(const bf16x8*)&Bs[wn * 32 + fn * 16 + (lane & 15)][8 * (lane >> 4)];
        #pragma unroll
        for (int fm = 0; fm < 4; ++fm)
            #pragma unroll
            for (int fn = 0; fn < 2; ++fn)
                acc[fm][fn] = __builtin_amdgcn_mfma_f32_16x16x32_bf16(af[fm], bfr[fn], acc[fm][fn], 0, 0, 0);
        __syncthreads();
    }

    #pragma unroll
    for (int fm = 0; fm < 4; ++fm) {
        #pragma unroll
        for (int fn = 0; fn < 2; ++fn) {
            #pragma unroll
            for (int r = 0; r < 4; ++r) {
                long grow = bm0 + wm * 64 + fm * 16 + (lane >> 4) * 4 + r;
                int gcol = n0 + wn * 32 + fn * 16 + (lane & 15);
                float v = acc[fm][fn][r] + bias[gcol];
                if (MODE == 0) {
                    outb[grow * (long)N + gcol] = f2b(v);
                } else if (MODE == 1) {
                    float gg = 0.5f * v * (1.0f + erff(v * 0.70710678118f));
                    outb[grow * (long)N + gcol] = f2b(gg);
                } else if (MODE == 2) {
                    if (grow < Mguard) {
                        int t = (int)grow;
                        int w = t / NTOK, n = t - w * NTOK;
                        int mlat = w / MLON, mlon = w - mlat * MLON;
                        int sh = mlat * WS + n / WS, sw = mlon * WS + (n % WS);
                        int hh = sh + SHIFT; if (hh >= HH) hh -= HH;
                        int wv = sw + SHIFT; if (wv >= WW) wv -= WW;
                        long p = (long)hh * WW + wv;
                        outf[p * CC + gcol] = resid[p * CC + gcol] + v;
                    }
                } else { // MODE 3
                    if (grow < Mguard) {
                        outf[grow * CC + gcol] += v;
                    }
                }
            }
        }
    }
}

// ---------------- attention: one wave per (window, head) ----------------
__global__ __launch_bounds__(64) void attn_kernel(
    const ushort_t* __restrict__ qkv,     // M_PAD x 576 bf16, cols: [3][NH][HD]
    const float* __restrict__ bias_table, // (3630, 6)
    ushort_t* __restrict__ av)            // M_PAD x 192 bf16
{
    __shared__ float    qs[NTOK][HD];
    __shared__ ushort_t ks[NTOK][HD];
    __shared__ ushort_t vs[NTOK][HD];
    __shared__ float    S[NTOK][NTOK];

    int blk = blockIdx.x;
    int w = blk / NH, h = blk - (blk / NH) * NH;
    int lane = threadIdx.x;
    int mlat = w / MLON, mlon = w - mlat * MLON;
    long base = (long)w * NTOK * 576;

    for (int e = lane; e < NTOK * HD; e += 64) {
        int n = e >> 5, d = e & 31;
        long idx = base + (long)n * 576 + h * HD + d;
        qs[n][d] = b2f(qkv[idx]) * SCALE_F;
        ks[n][d] = qkv[idx + 192];
        vs[n][d] = qkv[idx + 384];
    }
    __syncthreads();

    for (int e = lane; e < NTOK * NTOK; e += 64) {
        int i = e / NTOK, j = e - i * NTOK;
        float dot = 0.f;
        #pragma unroll
        for (int d = 0; d < HD; ++d) dot += qs[i][d] * b2f(ks[j][d]);
        int ih = i / WS, iw = i - ih * WS;
        int jh = j / WS, jw = j - jh * WS;
        int bidx = mlat * 121 + (ih - jh + 5) * 11 + (iw - jw + 5);
        float bv = bias_table[bidx * NH + h];
        int phi = mlat * WS + ih, pwi = mlon * WS + iw;
        int phj = mlat * WS + jh, pwj = mlon * WS + jw;
        int ri = (phi < HH - WS ? 0 : (phi < HH - SHIFT ? 1 : 2)) * 3
               + (pwi < WW - WS ? 0 : (pwi < WW - SHIFT ? 1 : 2));
        int rj = (phj < HH - WS ? 0 : (phj < HH - SHIFT ? 1 : 2)) * 3
               + (pwj < WW - WS ? 0 : (pwj < WW - SHIFT ? 1 : 2));
        float m = (ri != rj) ? -100.0f : 0.0f;
        S[i][j] = dot + bv + m;
    }
    __syncthreads();

    if (lane < NTOK) {
        float mx = -1e30f;
        #pragma unroll 4
        for (int j = 0; j < NTOK; ++j) mx = fmaxf(mx, S[lane][j]);
        float sum = 0.f;
        #pragma unroll 4
        for (int j = 0; j < NTOK; ++j) { float e2 = __expf(S[lane][j] - mx); S[lane][j] = e2; sum += e2; }
        float r = 1.0f / sum;
        #pragma unroll 4
        for (int j = 0; j < NTOK; ++j) S[lane][j] *= r;
    }
    __syncthreads();

    for (int e = lane; e < NTOK * HD; e += 64) {
        int i = e >> 5, d = e & 31;
        float o = 0.f;
        #pragma unroll 4
        for (int j = 0; j < NTOK; ++j) o += S[i][j] * b2f(vs[j][d]);
        av[((long)w * NTOK + i) * CC + h * HD + d] = f2b(o);
    }
}

// ---------------- launch ----------------
extern "C" void kernel_launch(void* const* d_in, const int* in_sizes, int n_in,
                              void* d_out, int out_size, void* d_ws, size_t ws_size,
                              hipStream_t stream) {
    const float* x        = (const float*)d_in[0];
    const float* n1w      = (const float*)d_in[1];
    const float* n1b      = (const float*)d_in[2];
    const float* qkv_w    = (const float*)d_in[3];
    const float* qkv_b    = (const float*)d_in[4];
    const float* proj_w   = (const float*)d_in[5];
    const float* proj_b   = (const float*)d_in[6];
    const float* btab     = (const float*)d_in[7];
    const float* n2w      = (const float*)d_in[8];
    const float* n2b      = (const float*)d_in[9];
    const float* fc1_w    = (const float*)d_in[10];
    const float* fc1_b    = (const float*)d_in[11];
    const float* fc2_w    = (const float*)d_in[12];
    const float* fc2_b    = (const float*)d_in[13];
    float* out = (float*)d_out;

    char* p = (char*)d_ws;
    ushort_t* xw  = (ushort_t*)p;  p += M_PAD * 192 * 2;   // LN1 out / later LN2 out
    ushort_t* big = (ushort_t*)p;  p += M_PAD * 768 * 2;   // qkv (576 cols) / later fc1 out (768 cols)
    ushort_t* av  = (ushort_t*)p;  p += M_PAD * 192 * 2;   // attention out
    ushort_t* wqkv = (ushort_t*)p; p += 576 * 192 * 2;
    ushort_t* wproj= (ushort_t*)p; p += 192 * 192 * 2;
    ushort_t* wfc1 = (ushort_t*)p; p += 768 * 192 * 2;
    ushort_t* wfc2 = (ushort_t*)p; p += 192 * 768 * 2;

    // weight transposes (K x N -> N x K, bf16)
    transpose_f2b<<<(576*192 + 255)/256, 256, 0, stream>>>(qkv_w, wqkv, 192, 576);
    transpose_f2b<<<(192*192 + 255)/256, 256, 0, stream>>>(proj_w, wproj, 192, 192);
    transpose_f2b<<<(768*192 + 255)/256, 256, 0, stream>>>(fc1_w, wfc1, 192, 768);
    transpose_f2b<<<(192*768 + 255)/256, 256, 0, stream>>>(fc2_w, wfc2, 768, 192);
    // zero pad rows of av (never written by attention)
    zero_bf16<<<(96*192 + 255)/256, 256, 0, stream>>>(av + M_TOK * 192, 96 * 192);

    // LN1 + shift + window partition
    ln1_window_kernel<<<M_PAD / 4, 256, 0, stream>>>(x, n1w, n1b, xw);

    // QKV: (M_PAD x 192) @ (192 x 576)
    gemm_bf16<0><<<dim3(M_PAD / BM, 576 / BN), 256, 0, stream>>>(
        xw, wqkv, qkv_b, big, nullptr, nullptr, 192, 576, M_PAD);

    // attention per (window, head)
    attn_kernel<<<NWIN * NH, 64, 0, stream>>>(big, btab, av);

    // proj + window reverse + residual -> out (fp32)
    gemm_bf16<2><<<dim3(M_PAD / BM, 192 / BN), 256, 0, stream>>>(
        av, wproj, proj_b, nullptr, out, x, 192, 192, M_TOK);

    // LN2 on out -> xw (reuse)
    ln2_kernel<<<M_PAD / 4, 256, 0, stream>>>(out, n2w, n2b, xw);

    // FC1 + GELU: (M_PAD x 192) @ (192 x 768)
    gemm_bf16<1><<<dim3(M_PAD / BM, 768 / BN), 256, 0, stream>>>(
        xw, wfc1, fc1_b, big, nullptr, nullptr, 192, 768, M_PAD);

    // FC2 + residual accumulate into out
    gemm_bf16<3><<<dim3(M_PAD / BM, 192 / BN), 256, 0, stream>>>(
        big, wfc2, fc2_b, nullptr, out, nullptr, 768, 192, M_TOK);
}

// Round 2
// 311.151 us; speedup vs baseline: 1.2883x; 1.2883x over previous
//
#include <hip/hip_runtime.h>
#include <hip/hip_bf16.h>

// ---------------- constants ----------------
constexpr int HH   = 180;
constexpr int WW   = 360;
constexpr int CC   = 192;
constexpr int WS   = 6;
constexpr int SHIFT= 3;
constexpr int NH   = 6;
constexpr int MLAT = HH / WS;   // 30
constexpr int MLON = WW / WS;   // 60
constexpr int NWIN = MLAT * MLON; // 1800
constexpr int NTOK = WS * WS;   // 36
constexpr int HD   = CC / NH;   // 32
constexpr long M_TOK = (long)NWIN * NTOK;  // 64800
constexpr long M_PAD = 64896;              // 507 * 128
constexpr float SCALE_F = 0.17677669529663687f; // 32^-0.5

typedef unsigned short ushort_t;
using bf16x8 = __attribute__((ext_vector_type(8))) short;
using f32x4  = __attribute__((ext_vector_type(4))) float;

static __device__ inline float b2f(ushort_t u) {
    union { float f; unsigned int i; } v; v.i = ((unsigned int)u) << 16; return v.f;
}
static __device__ inline ushort_t f2b(float f) {
    union { float f; unsigned int i; } v; v.f = f;
    unsigned int r = v.i + 0x7FFFu + ((v.i >> 16) & 1u);
    return (ushort_t)(r >> 16);
}

static __device__ inline void gload_lds16(const ushort_t* g, ushort_t* l) {
    __builtin_amdgcn_global_load_lds(
        (const __attribute__((address_space(1))) unsigned int*)g,
        (__attribute__((address_space(3))) unsigned int*)l, 16, 0, 0);
}

// ---------------- weight transpose + bf16 convert ----------------
__global__ void transpose_f2b(const float* __restrict__ in, ushort_t* __restrict__ out,
                              int K, int N) {
    int e = blockIdx.x * 256 + threadIdx.x;
    if (e >= K * N) return;
    int n = e / K, k = e - n * K;
    out[e] = f2b(in[(long)k * N + n]);
}

__global__ void zero_bf16(ushort_t* __restrict__ p, int count) {
    int e = blockIdx.x * 256 + threadIdx.x;
    if (e < count) p[e] = 0;
}

// ---------------- bias+mask precompute: (MLAT, 2, NH, 36, 36) fp32 ----------------
static __device__ inline int region1d(int p, int L) {
    return (p < L - WS) ? 0 : ((p < L - SHIFT) ? 1 : 2);
}

__global__ void bias_mask_precompute(const float* __restrict__ bt, float* __restrict__ bm) {
    int idx = blockIdx.x * 256 + threadIdx.x;
    if (idx >= MLAT * 2 * NH * NTOK * NTOK) return;
    int e = idx;
    int ij = e % (NTOK * NTOK); e /= (NTOK * NTOK);
    int h = e % NH; e /= NH;
    int lt = e % 2;
    int mlat = e / 2;
    int i = ij / NTOK, j = ij - (ij / NTOK) * NTOK;
    int ih = i / WS, iw = i - ih * WS;
    int jh = j / WS, jw = j - jh * WS;
    int bidx = mlat * 121 + (ih - jh + 5) * 11 + (iw - jw + 5);
    float v = bt[bidx * NH + h];
    int mlon = lt ? (MLON - 1) : 0;
    int ri = region1d(mlat * WS + ih, HH) * 3 + region1d(mlon * WS + iw, WW);
    int rj = region1d(mlat * WS + jh, HH) * 3 + region1d(mlon * WS + jw, WW);
    if (ri != rj) v += -100.0f;
    bm[idx] = v;
}

// ---------------- LN1 + cyclic shift + window partition -> bf16 ----------------
__global__ __launch_bounds__(256) void ln1_window_kernel(
    const float* __restrict__ x, const float* __restrict__ g, const float* __restrict__ b,
    ushort_t* __restrict__ xw)
{
    long t = (long)blockIdx.x * 4 + (threadIdx.x >> 6);
    int lane = threadIdx.x & 63;
    if (t >= M_PAD) return;
    if (t >= M_TOK) {
        ushort_t* o = xw + t * CC;
        o[lane] = 0; o[lane + 64] = 0; o[lane + 128] = 0;
        return;
    }
    int ti = (int)t;
    int w = ti / NTOK, n = ti - w * NTOK;
    int mlat = w / MLON, mlon = w - mlat * MLON;
    int sh = mlat * WS + n / WS, sw = mlon * WS + (n % WS);
    int hh = sh + SHIFT; if (hh >= HH) hh -= HH;
    int ww = sw + SHIFT; if (ww >= WW) ww -= WW;
    const float* row = x + ((long)hh * WW + ww) * CC;
    float v0 = row[lane], v1 = row[lane + 64], v2 = row[lane + 128];
    float s = v0 + v1 + v2;
    float ss = v0 * v0 + v1 * v1 + v2 * v2;
    #pragma unroll
    for (int o = 32; o > 0; o >>= 1) { s += __shfl_xor(s, o, 64); ss += __shfl_xor(ss, o, 64); }
    float mu = s * (1.0f / CC);
    float var = ss * (1.0f / CC) - mu * mu;
    float rinv = rsqrtf(var + 1e-5f);
    ushort_t* o = xw + t * CC;
    o[lane]       = f2b((v0 - mu) * rinv * g[lane]       + b[lane]);
    o[lane + 64]  = f2b((v1 - mu) * rinv * g[lane + 64]  + b[lane + 64]);
    o[lane + 128] = f2b((v2 - mu) * rinv * g[lane + 128] + b[lane + 128]);
}

// ---------------- LN2 (identity mapping) ----------------
__global__ __launch_bounds__(256) void ln2_kernel(
    const float* __restrict__ xin, const float* __restrict__ g, const float* __restrict__ b,
    ushort_t* __restrict__ h2)
{
    long t = (long)blockIdx.x * 4 + (threadIdx.x >> 6);
    int lane = threadIdx.x & 63;
    if (t >= M_PAD) return;
    if (t >= M_TOK) {
        ushort_t* o = h2 + t * CC;
        o[lane] = 0; o[lane + 64] = 0; o[lane + 128] = 0;
        return;
    }
    const float* row = xin + t * CC;
    float v0 = row[lane], v1 = row[lane + 64], v2 = row[lane + 128];
    float s = v0 + v1 + v2;
    float ss = v0 * v0 + v1 * v1 + v2 * v2;
    #pragma unroll
    for (int o = 32; o > 0; o >>= 1) { s += __shfl_xor(s, o, 64); ss += __shfl_xor(ss, o, 64); }
    float mu = s * (1.0f / CC);
    float var = ss * (1.0f / CC) - mu * mu;
    float rinv = rsqrtf(var + 1e-5f);
    ushort_t* o = h2 + t * CC;
    o[lane]       = f2b((v0 - mu) * rinv * g[lane]       + b[lane]);
    o[lane + 64]  = f2b((v1 - mu) * rinv * g[lane + 64]  + b[lane + 64]);
    o[lane + 128] = f2b((v2 - mu) * rinv * g[lane + 128] + b[lane + 128]);
}

// ---------------- MFMA GEMM ----------------
#define BM 128
#define BN 64
#define BK 32

template<int MODE>
__global__ __launch_bounds__(256) void gemm_bf16(
    const ushort_t* __restrict__ A, const ushort_t* __restrict__ Bt,
    const float* __restrict__ bias,
    ushort_t* __restrict__ outb, float* __restrict__ outf,
    const float* __restrict__ resid,
    int K, int N, long Mguard)
{
    __shared__ __align__(16) ushort_t As[BM][BK];
    __shared__ __align__(16) ushort_t Bs[BN][BK];
    int tid = threadIdx.x;
    int lane = tid & 63;
    int wid = tid >> 6;
    int wm = wid >> 1, wn = wid & 1;
    long bm0 = (long)blockIdx.x * BM;
    int n0 = blockIdx.y * BN;

    f32x4 acc[4][2] = {};

    int arow = tid >> 2, aseg = tid & 3;

    int nk = K / BK;
    for (int kt = 0; kt < nk; ++kt) {
        int k0 = kt * BK;
        // async global -> LDS staging (dest offsets are exactly tid*16: linear)
        gload_lds16(&A[(bm0 + arow) * K + k0 + aseg * 8], &As[arow][aseg * 8]);
        gload_lds16(&A[(bm0 + 64 + arow) * K + k0 + aseg * 8], &As[64 + arow][aseg * 8]);
        gload_lds16(&Bt[(long)(n0 + arow) * K + k0 + aseg * 8], &Bs[arow][aseg * 8]);
        __syncthreads();
        bf16x8 af[4], bfr[2];
        #pragma unroll
        for (int fm = 0; fm < 4; ++fm)
            af[fm] = *(const bf16x8*)&As[wm * 64 + fm * 16 + (lane & 15)][8 * (lane >> 4)];
        #pragma unroll
        for (int fn = 0; fn < 2; ++fn)
            bfr[fn] = *(const bf16x8*)&Bs[wn * 32 + fn * 16 + (lane & 15)][8 * (lane >> 4)];
        #pragma unroll
        for (int fm = 0; fm < 4; ++fm)
            #pragma unroll
            for (int fn = 0; fn < 2; ++fn)
                acc[fm][fn] = __builtin_amdgcn_mfma_f32_16x16x32_bf16(af[fm], bfr[fn], acc[fm][fn], 0, 0, 0);
        __syncthreads();
    }

    #pragma unroll
    for (int fm = 0; fm < 4; ++fm) {
        #pragma unroll
        for (int fn = 0; fn < 2; ++fn) {
            #pragma unroll
            for (int r = 0; r < 4; ++r) {
                long grow = bm0 + wm * 64 + fm * 16 + (lane >> 4) * 4 + r;
                int gcol = n0 + wn * 32 + fn * 16 + (lane & 15);
                float v = acc[fm][fn][r] + bias[gcol];
                if (MODE == 0) {
                    outb[grow * (long)N + gcol] = f2b(v);
                } else if (MODE == 1) {
                    float gg = 0.5f * v * (1.0f + erff(v * 0.70710678118f));
                    outb[grow * (long)N + gcol] = f2b(gg);
                } else if (MODE == 2) {
                    if (grow < Mguard) {
                        int t = (int)grow;
                        int w = t / NTOK, n = t - w * NTOK;
                        int mlat = w / MLON, mlon = w - mlat * MLON;
                        int sh = mlat * WS + n / WS, sw = mlon * WS + (n % WS);
                        int hh = sh + SHIFT; if (hh >= HH) hh -= HH;
                        int wv = sw + SHIFT; if (wv >= WW) wv -= WW;
                        long p = (long)hh * WW + wv;
                        outf[p * CC + gcol] = resid[p * CC + gcol] + v;
                    }
                } else { // MODE 3
                    if (grow < Mguard) {
                        outf[grow * CC + gcol] += v;
                    }
                }
            }
        }
    }
}

// ---------------- MFMA attention: one wave per (window, head), 4 waves/block ----------------
__global__ __launch_bounds__(256) void attn_mfma_kernel(
    const ushort_t* __restrict__ qkv,     // M_PAD x 576 bf16, cols [3][NH][HD]
    const float* __restrict__ bm,         // (MLAT, 2, NH, 36, 36) fp32 bias+mask
    ushort_t* __restrict__ av)            // M_PAD x 192 bf16
{
    __shared__ __align__(16) ushort_t Pls[4][48][72];   // P, padded stride
    __shared__ __align__(16) ushort_t Vt[4][32][72];    // V^T (d, tok), padded

    int wid = threadIdx.x >> 6, lane = threadIdx.x & 63;
    int unit = blockIdx.x * 4 + wid;
    int w = unit / NH, h = unit - (unit / NH) * NH;
    int mlat = w / MLON, mlon = w - mlat * MLON;
    int lr = lane & 15, lg = lane >> 4;

    const ushort_t* Qb = qkv + (long)w * NTOK * 576 + h * HD;
    const ushort_t* Kb = Qb + 192;
    const ushort_t* Vb = Qb + 384;

    bf16x8 zero8 = {0,0,0,0,0,0,0,0};

    // ---- QK^T: A = Q rows, B = K rows (B[k][n] = K[n][k] matches frag layout) ----
    bf16x8 qf[3], kf[3];
    #pragma unroll
    for (int t = 0; t < 3; ++t) {
        int row = t * 16 + lr;
        qf[t] = (row < NTOK) ? *(const bf16x8*)&Qb[(long)row * 576 + 8 * lg] : zero8;
        kf[t] = (row < NTOK) ? *(const bf16x8*)&Kb[(long)row * 576 + 8 * lg] : zero8;
    }
    f32x4 s[3][3] = {};
    #pragma unroll
    for (int mt = 0; mt < 3; ++mt)
        #pragma unroll
        for (int nt = 0; nt < 3; ++nt)
            s[mt][nt] = __builtin_amdgcn_mfma_f32_16x16x32_bf16(qf[mt], kf[nt], s[mt][nt], 0, 0, 0);

    // ---- bias + mask + softmax (wave-parallel; rows live in 16 lanes x 3 values) ----
    const float* bb = bm + (((mlat * 2 + (mlon == MLON - 1)) * NH) + h) * (NTOK * NTOK);
    bool jv[3];
    #pragma unroll
    for (int nt = 0; nt < 3; ++nt) jv[nt] = (nt * 16 + lr) < NTOK;

    #pragma unroll
    for (int mt = 0; mt < 3; ++mt) {
        #pragma unroll
        for (int r = 0; r < 4; ++r) {
            int i = mt * 16 + lg * 4 + r;
            float v[3];
            #pragma unroll
            for (int nt = 0; nt < 3; ++nt) {
                int j = nt * 16 + lr;
                float t = s[mt][nt][r] * SCALE_F;
                if (i < NTOK && j < NTOK) t += bb[i * NTOK + j];
                v[nt] = t;
            }
            float mx = -1e30f;
            #pragma unroll
            for (int nt = 0; nt < 3; ++nt) if (jv[nt]) mx = fmaxf(mx, v[nt]);
            #pragma unroll
            for (int o = 1; o < 16; o <<= 1) mx = fmaxf(mx, __shfl_xor(mx, o, 64));
            float e[3], sum = 0.f;
            #pragma unroll
            for (int nt = 0; nt < 3; ++nt) { e[nt] = jv[nt] ? __expf(v[nt] - mx) : 0.f; sum += e[nt]; }
            #pragma unroll
            for (int o = 1; o < 16; o <<= 1) sum += __shfl_xor(sum, o, 64);
            float rs = 1.0f / sum;
            #pragma unroll
            for (int nt = 0; nt < 3; ++nt) s[mt][nt][r] = e[nt] * rs;
        }
    }

    // ---- write P to LDS (bf16), zero pad cols 48..63 ----
    #pragma unroll
    for (int mt = 0; mt < 3; ++mt)
        #pragma unroll
        for (int nt = 0; nt < 3; ++nt)
            #pragma unroll
            for (int r = 0; r < 4; ++r)
                Pls[wid][mt * 16 + lg * 4 + r][nt * 16 + lr] = f2b(s[mt][nt][r]);
    #pragma unroll
    for (int it = 0; it < 2; ++it) {
        int idx = it * 64 + lane;
        if (idx < 96) {
            int row = idx >> 1, hf = idx & 1;
            *(uint4*)&Pls[wid][row][48 + hf * 8] = uint4{0, 0, 0, 0};
        }
    }

    // ---- stage V transposed: Vt[d][tok]; zero toks 36..67 ----
    #pragma unroll
    for (int it = 0; it < 8; ++it) {
        int idx = it * 64 + lane;
        int row = idx >> 4, c = idx & 15;
        *(unsigned int*)&Vt[wid][row][36 + c * 2] = 0u;
    }
    #pragma unroll
    for (int it = 0; it < 9; ++it) {
        int e = it * 64 + lane;
        int tok = e >> 4, dp = e & 15;
        unsigned int v2 = *(const unsigned int*)&Vb[(long)tok * 576 + dp * 2];
        Vt[wid][dp * 2][tok]     = (ushort_t)(v2 & 0xffffu);
        Vt[wid][dp * 2 + 1][tok] = (ushort_t)(v2 >> 16);
    }

    // ---- PV: A = P (48 x 64), B = V (64 x 32) via Vt ----
    f32x4 o[3][2] = {};
    #pragma unroll
    for (int kt = 0; kt < 2; ++kt) {
        bf16x8 pa[3], vb[2];
        #pragma unroll
        for (int mt = 0; mt < 3; ++mt)
            pa[mt] = *(const bf16x8*)&Pls[wid][mt * 16 + lr][kt * 32 + 8 * lg];
        #pragma unroll
        for (int nd = 0; nd < 2; ++nd)
            vb[nd] = *(const bf16x8*)&Vt[wid][nd * 16 + lr][kt * 32 + 8 * lg];
        #pragma unroll
        for (int mt = 0; mt < 3; ++mt)
            #pragma unroll
            for (int nd = 0; nd < 2; ++nd)
                o[mt][nd] = __builtin_amdgcn_mfma_f32_16x16x32_bf16(pa[mt], vb[nd], o[mt][nd], 0, 0, 0);
    }

    // ---- write out ----
    #pragma unroll
    for (int mt = 0; mt < 3; ++mt)
        #pragma unroll
        for (int nd = 0; nd < 2; ++nd)
            #pragma unroll
            for (int r = 0; r < 4; ++r) {
                int i = mt * 16 + lg * 4 + r;
                if (i < NTOK)
                    av[((long)w * NTOK + i) * CC + h * HD + nd * 16 + lr] = f2b(o[mt][nd][r]);
            }
}

// ---------------- launch ----------------
extern "C" void kernel_launch(void* const* d_in, const int* in_sizes, int n_in,
                              void* d_out, int out_size, void* d_ws, size_t ws_size,
                              hipStream_t stream) {
    const float* x        = (const float*)d_in[0];
    const float* n1w      = (const float*)d_in[1];
    const float* n1b      = (const float*)d_in[2];
    const float* qkv_w    = (const float*)d_in[3];
    const float* qkv_b    = (const float*)d_in[4];
    const float* proj_w   = (const float*)d_in[5];
    const float* proj_b   = (const float*)d_in[6];
    const float* btab     = (const float*)d_in[7];
    const float* n2w      = (const float*)d_in[8];
    const float* n2b      = (const float*)d_in[9];
    const float* fc1_w    = (const float*)d_in[10];
    const float* fc1_b    = (const float*)d_in[11];
    const float* fc2_w    = (const float*)d_in[12];
    const float* fc2_b    = (const float*)d_in[13];
    float* out = (float*)d_out;

    char* p = (char*)d_ws;
    ushort_t* xw  = (ushort_t*)p;  p += M_PAD * 192 * 2;
    ushort_t* big = (ushort_t*)p;  p += M_PAD * 768 * 2;
    ushort_t* av  = (ushort_t*)p;  p += M_PAD * 192 * 2;
    ushort_t* wqkv = (ushort_t*)p; p += 576 * 192 * 2;
    ushort_t* wproj= (ushort_t*)p; p += 192 * 192 * 2;
    ushort_t* wfc1 = (ushort_t*)p; p += 768 * 192 * 2;
    ushort_t* wfc2 = (ushort_t*)p; p += 192 * 768 * 2;
    float*    bmask= (float*)p;    p += MLAT * 2 * NH * NTOK * NTOK * 4;

    transpose_f2b<<<(576*192 + 255)/256, 256, 0, stream>>>(qkv_w, wqkv, 192, 576);
    transpose_f2b<<<(192*192 + 255)/256, 256, 0, stream>>>(proj_w, wproj, 192, 192);
    transpose_f2b<<<(768*192 + 255)/256, 256, 0, stream>>>(fc1_w, wfc1, 192, 768);
    transpose_f2b<<<(192*768 + 255)/256, 256, 0, stream>>>(fc2_w, wfc2, 768, 192);
    bias_mask_precompute<<<(MLAT*2*NH*NTOK*NTOK + 255)/256, 256, 0, stream>>>(btab, bmask);
    zero_bf16<<<(96*192 + 255)/256, 256, 0, stream>>>(av + M_TOK * 192, 96 * 192);

    ln1_window_kernel<<<M_PAD / 4, 256, 0, stream>>>(x, n1w, n1b, xw);

    gemm_bf16<0><<<dim3(M_PAD / BM, 576 / BN), 256, 0, stream>>>(
        xw, wqkv, qkv_b, big, nullptr, nullptr, 192, 576, M_PAD);

    attn_mfma_kernel<<<NWIN * NH / 4, 256, 0, stream>>>(big, bmask, av);

    gemm_bf16<2><<<dim3(M_PAD / BM, 192 / BN), 256, 0, stream>>>(
        av, wproj, proj_b, nullptr, out, x, 192, 192, M_TOK);

    ln2_kernel<<<M_PAD / 4, 256, 0, stream>>>(out, n2w, n2b, xw);

    gemm_bf16<1><<<dim3(M_PAD / BM, 768 / BN), 256, 0, stream>>>(
        xw, wfc1, fc1_b, big, nullptr, nullptr, 192, 768, M_PAD);

    gemm_bf16<3><<<dim3(M_PAD / BM, 192 / BN), 256, 0, stream>>>(
        big, wfc2, fc2_b, nullptr, out, nullptr, 768, 192, M_TOK);
}

// Round 3
// 231.930 us; speedup vs baseline: 1.7283x; 1.3416x over previous
//
#include <hip/hip_runtime.h>
#include <hip/hip_bf16.h>

// ---------------- constants ----------------
constexpr int HH   = 180;
constexpr int WW   = 360;
constexpr int CC   = 192;
constexpr int WS   = 6;
constexpr int SHIFT= 3;
constexpr int NH   = 6;
constexpr int MLAT = HH / WS;   // 30
constexpr int MLON = WW / WS;   // 60
constexpr int NWIN = MLAT * MLON; // 1800
constexpr int NTOK = WS * WS;   // 36
constexpr int HD   = CC / NH;   // 32
constexpr long M_TOK = (long)NWIN * NTOK;  // 64800
constexpr long M_PAD = 64896;              // 507 * 128
constexpr float SCALE_F = 0.17677669529663687f; // 32^-0.5

typedef unsigned short ushort_t;
using bf16x8 = __attribute__((ext_vector_type(8))) short;
using f32x4  = __attribute__((ext_vector_type(4))) float;

static __device__ inline float b2f(ushort_t u) {
    union { float f; unsigned int i; } v; v.i = ((unsigned int)u) << 16; return v.f;
}
static __device__ inline ushort_t f2b(float f) {
    union { float f; unsigned int i; } v; v.f = f;
    unsigned int r = v.i + 0x7FFFu + ((v.i >> 16) & 1u);
    return (ushort_t)(r >> 16);
}

static __device__ inline void gload_lds16(const ushort_t* g, ushort_t* l) {
    __builtin_amdgcn_global_load_lds(
        (const __attribute__((address_space(1))) unsigned int*)g,
        (__attribute__((address_space(3))) unsigned int*)l, 16, 0, 0);
}

// ---------------- weight transpose + bf16 convert ----------------
__global__ void transpose_f2b(const float* __restrict__ in, ushort_t* __restrict__ out,
                              int K, int N) {
    int e = blockIdx.x * 256 + threadIdx.x;
    if (e >= K * N) return;
    int n = e / K, k = e - n * K;
    out[e] = f2b(in[(long)k * N + n]);
}

__global__ void zero_bf16(ushort_t* __restrict__ p, int count) {
    int e = blockIdx.x * 256 + threadIdx.x;
    if (e < count) p[e] = 0;
}

// ---------------- bias+mask precompute: (MLAT, 2, NH, 36, 36) fp32 ----------------
static __device__ inline int region1d(int p, int L) {
    return (p < L - WS) ? 0 : ((p < L - SHIFT) ? 1 : 2);
}

__global__ void bias_mask_precompute(const float* __restrict__ bt, float* __restrict__ bm) {
    int idx = blockIdx.x * 256 + threadIdx.x;
    if (idx >= MLAT * 2 * NH * NTOK * NTOK) return;
    int e = idx;
    int ij = e % (NTOK * NTOK); e /= (NTOK * NTOK);
    int h = e % NH; e /= NH;
    int lt = e % 2;
    int mlat = e / 2;
    int i = ij / NTOK, j = ij - (ij / NTOK) * NTOK;
    int ih = i / WS, iw = i - ih * WS;
    int jh = j / WS, jw = j - jh * WS;
    int bidx = mlat * 121 + (ih - jh + 5) * 11 + (iw - jw + 5);
    float v = bt[bidx * NH + h];
    int mlon = lt ? (MLON - 1) : 0;
    int ri = region1d(mlat * WS + ih, HH) * 3 + region1d(mlon * WS + iw, WW);
    int rj = region1d(mlat * WS + jh, HH) * 3 + region1d(mlon * WS + jw, WW);
    if (ri != rj) v += -100.0f;
    bm[idx] = v;
}

// ---------------- LN1 + cyclic shift + window partition -> bf16 ----------------
__global__ __launch_bounds__(256) void ln1_window_kernel(
    const float* __restrict__ x, const float* __restrict__ g, const float* __restrict__ b,
    ushort_t* __restrict__ xw)
{
    long t = (long)blockIdx.x * 4 + (threadIdx.x >> 6);
    int lane = threadIdx.x & 63;
    if (t >= M_PAD) return;
    if (t >= M_TOK) {
        ushort_t* o = xw + t * CC;
        o[lane] = 0; o[lane + 64] = 0; o[lane + 128] = 0;
        return;
    }
    int ti = (int)t;
    int w = ti / NTOK, n = ti - w * NTOK;
    int mlat = w / MLON, mlon = w - mlat * MLON;
    int sh = mlat * WS + n / WS, sw = mlon * WS + (n % WS);
    int hh = sh + SHIFT; if (hh >= HH) hh -= HH;
    int ww = sw + SHIFT; if (ww >= WW) ww -= WW;
    const float* row = x + ((long)hh * WW + ww) * CC;
    float v0 = row[lane], v1 = row[lane + 64], v2 = row[lane + 128];
    float s = v0 + v1 + v2;
    float ss = v0 * v0 + v1 * v1 + v2 * v2;
    #pragma unroll
    for (int o = 32; o > 0; o >>= 1) { s += __shfl_xor(s, o, 64); ss += __shfl_xor(ss, o, 64); }
    float mu = s * (1.0f / CC);
    float var = ss * (1.0f / CC) - mu * mu;
    float rinv = rsqrtf(var + 1e-5f);
    ushort_t* o = xw + t * CC;
    o[lane]       = f2b((v0 - mu) * rinv * g[lane]       + b[lane]);
    o[lane + 64]  = f2b((v1 - mu) * rinv * g[lane + 64]  + b[lane + 64]);
    o[lane + 128] = f2b((v2 - mu) * rinv * g[lane + 128] + b[lane + 128]);
}

// ---------------- LN2 (identity mapping) ----------------
__global__ __launch_bounds__(256) void ln2_kernel(
    const float* __restrict__ xin, const float* __restrict__ g, const float* __restrict__ b,
    ushort_t* __restrict__ h2)
{
    long t = (long)blockIdx.x * 4 + (threadIdx.x >> 6);
    int lane = threadIdx.x & 63;
    if (t >= M_PAD) return;
    if (t >= M_TOK) {
        ushort_t* o = h2 + t * CC;
        o[lane] = 0; o[lane + 64] = 0; o[lane + 128] = 0;
        return;
    }
    const float* row = xin + t * CC;
    float v0 = row[lane], v1 = row[lane + 64], v2 = row[lane + 128];
    float s = v0 + v1 + v2;
    float ss = v0 * v0 + v1 * v1 + v2 * v2;
    #pragma unroll
    for (int o = 32; o > 0; o >>= 1) { s += __shfl_xor(s, o, 64); ss += __shfl_xor(ss, o, 64); }
    float mu = s * (1.0f / CC);
    float var = ss * (1.0f / CC) - mu * mu;
    float rinv = rsqrtf(var + 1e-5f);
    ushort_t* o = h2 + t * CC;
    o[lane]       = f2b((v0 - mu) * rinv * g[lane]       + b[lane]);
    o[lane + 64]  = f2b((v1 - mu) * rinv * g[lane + 64]  + b[lane + 64]);
    o[lane + 128] = f2b((v2 - mu) * rinv * g[lane + 128] + b[lane + 128]);
}

// ---------------- MFMA GEMM: BM=128, BN=192, BK=32, 2-phase dbuf ----------------
// MODE 0: outb = bf16(acc + bias)                      (QKV)
// MODE 1: outb = bf16(gelu(acc + bias))                (FC1)
// MODE 2: out fp32 scatter: window-reverse + residual  (proj)
// MODE 3: outf[row] += acc + bias                      (FC2)
#define BM 128
#define BN 192
#define BK 32

template<int MODE>
__global__ __launch_bounds__(256, 2) void gemm_bf16(
    const ushort_t* __restrict__ A, const ushort_t* __restrict__ Bt,
    const float* __restrict__ bias,
    ushort_t* __restrict__ outb, float* __restrict__ outf,
    const float* __restrict__ resid,
    int K, int N, long Mguard, int ncol, int nwg)
{
    // 2 buffers x (As 128x32 + Bs 192x32) bf16 = 40960 B
    __shared__ __align__(16) ushort_t lds[20480];
    __shared__ int row_map[BM];

    int tid = threadIdx.x;
    int lane = tid & 63;
    int wid = tid >> 6;
    int lr = lane & 15, lg = lane >> 4;
    int wm = wid >> 1, wn = wid & 1;

    // bijective XCD swizzle (m204), column-fastest decomposition
    int orig = blockIdx.x;
    int q = nwg >> 3, r8 = nwg & 7;
    int xcd = orig & 7, pos = orig >> 3;
    int wg = (xcd < r8 ? xcd * (q + 1) : r8 * (q + 1) + (xcd - r8) * q) + pos;
    int brow = wg / ncol, bcol = wg - brow * ncol;
    long bm0 = (long)brow * BM;
    int n0 = bcol * BN;

    if (MODE == 2 && tid < BM) {
        long t = bm0 + tid;
        if (t < M_TOK) {
            int ti = (int)t;
            int w = ti / NTOK, n = ti - w * NTOK;
            int mlat = w / MLON, mlon = w - mlat * MLON;
            int sh = mlat * WS + n / WS, sw = mlon * WS + (n % WS);
            int hh = sh + SHIFT; if (hh >= HH) hh -= HH;
            int wv = sw + SHIFT; if (wv >= WW) wv -= WW;
            row_map[tid] = hh * WW + wv;
        } else row_map[tid] = -1;
    }

    int arow = tid >> 2, aseg = tid & 3;
    const ushort_t* pa0 = A  + (bm0 + arow) * K + aseg * 8;
    const ushort_t* pa1 = pa0 + 64 * (long)K;
    const ushort_t* pb0 = Bt + (long)(n0 + arow) * K + aseg * 8;
    const ushort_t* pb1 = pb0 + 64 * (long)K;
    const ushort_t* pb2 = pb0 + 128 * (long)K;

#define STAGE(b, koff) do { \
    ushort_t* Asb = lds + (b) * 10240; \
    ushort_t* Bsb = Asb + 4096; \
    gload_lds16(pa0 + (koff), Asb + tid * 8); \
    gload_lds16(pa1 + (koff), Asb + 2048 + tid * 8); \
    gload_lds16(pb0 + (koff), Bsb + tid * 8); \
    gload_lds16(pb1 + (koff), Bsb + 2048 + tid * 8); \
    gload_lds16(pb2 + (koff), Bsb + 4096 + tid * 8); \
} while (0)

    f32x4 acc[4][6] = {};

    STAGE(0, 0);
    __syncthreads();

    int nk = K / BK;
    for (int kt = 0; kt < nk; ++kt) {
        if (kt + 1 < nk) STAGE((kt + 1) & 1, (kt + 1) * BK);
        const ushort_t* Asb = lds + (kt & 1) * 10240;
        const ushort_t* Bsb = Asb + 4096;
        bf16x8 af[4], bfr[6];
        #pragma unroll
        for (int fm = 0; fm < 4; ++fm)
            af[fm] = *(const bf16x8*)&Asb[(wm * 64 + fm * 16 + lr) * 32 + 8 * lg];
        #pragma unroll
        for (int fn = 0; fn < 6; ++fn)
            bfr[fn] = *(const bf16x8*)&Bsb[(wn * 96 + fn * 16 + lr) * 32 + 8 * lg];
        #pragma unroll
        for (int fm = 0; fm < 4; ++fm)
            #pragma unroll
            for (int fn = 0; fn < 6; ++fn)
                acc[fm][fn] = __builtin_amdgcn_mfma_f32_16x16x32_bf16(af[fm], bfr[fn], acc[fm][fn], 0, 0, 0);
        __syncthreads();
    }
#undef STAGE

    // ---- epilogue with LDS bounce (per-wave private region) ----
    float bv[6];
    #pragma unroll
    for (int fn = 0; fn < 6; ++fn) bv[fn] = bias[n0 + wn * 96 + fn * 16 + lr];

    if (MODE == 0 || MODE == 1) {
        ushort_t* bb = lds + wid * 1536;   // 16 x 96 bf16
        #pragma unroll
        for (int fm = 0; fm < 4; ++fm) {
            #pragma unroll
            for (int fn = 0; fn < 6; ++fn) {
                int pcfn = fn + lg; if (pcfn >= 6) pcfn -= 6;   // bank rotation
                #pragma unroll
                for (int r = 0; r < 4; ++r) {
                    float v = acc[fm][fn][r] + bv[fn];
                    if (MODE == 1) v = 0.5f * v * (1.0f + erff(v * 0.70710678118f));
                    bb[(lg * 4 + r) * 96 + pcfn * 16 + lr] = f2b(v);
                }
            }
            #pragma unroll
            for (int i = 0; i < 3; ++i) {
                int cid = i * 64 + lane;
                int row = cid / 12, c8 = cid - row * 12;
                int pc8 = c8 + 2 * (row >> 2); if (pc8 >= 12) pc8 -= 12;
                uint4 val = *(const uint4*)&bb[row * 96 + pc8 * 8];
                long grow = bm0 + wm * 64 + fm * 16 + row;
                *(uint4*)&outb[grow * (long)N + n0 + wn * 96 + c8 * 8] = val;
            }
        }
    } else {
        float* fb = (float*)lds + wid * 1536;   // 16 x 96 f32
        #pragma unroll
        for (int fm = 0; fm < 4; ++fm) {
            #pragma unroll
            for (int fn = 0; fn < 6; ++fn) {
                int pcfn = fn + lg; if (pcfn >= 6) pcfn -= 6;
                #pragma unroll
                for (int r = 0; r < 4; ++r)
                    fb[(lg * 4 + r) * 96 + pcfn * 16 + lr] = acc[fm][fn][r] + bv[fn];
            }
            #pragma unroll
            for (int i = 0; i < 6; ++i) {
                int cid = i * 64 + lane;
                int row = cid / 24, c4 = cid - row * 24;
                int pc4 = c4 + 4 * (row >> 2); if (pc4 >= 24) pc4 -= 24;
                f32x4 val = *(const f32x4*)&fb[row * 96 + pc4 * 4];
                int lrow = wm * 64 + fm * 16 + row;
                int col = wn * 96 + c4 * 4;
                if (MODE == 3) {
                    long grow = bm0 + lrow;
                    if (grow < Mguard) {
                        float* p = &outf[grow * 192 + col];
                        f32x4 old = *(const f32x4*)p;
                        *(f32x4*)p = old + val;
                    }
                } else { // MODE 2
                    int pp = row_map[lrow];
                    if (pp >= 0) {
                        const float* rp = &resid[(long)pp * 192 + col];
                        f32x4 rv = *(const f32x4*)rp;
                        *(f32x4*)&outf[(long)pp * 192 + col] = rv + val;
                    }
                }
            }
        }
    }
}

// ---------------- MFMA attention: one wave per (window, head), 4 waves/block ----------------
__global__ __launch_bounds__(256) void attn_mfma_kernel(
    const ushort_t* __restrict__ qkv,     // M_PAD x 576 bf16, cols [3][NH][HD]
    const float* __restrict__ bm,         // (MLAT, 2, NH, 36, 36) fp32 bias+mask
    ushort_t* __restrict__ av)            // M_PAD x 192 bf16
{
    __shared__ __align__(16) ushort_t Pls[4][48][72];   // P, padded stride
    __shared__ __align__(16) ushort_t Vt[4][32][72];    // V^T (d, tok), padded

    int wid = threadIdx.x >> 6, lane = threadIdx.x & 63;
    int unit = blockIdx.x * 4 + wid;
    int w = unit / NH, h = unit - (unit / NH) * NH;
    int mlat = w / MLON, mlon = w - mlat * MLON;
    int lr = lane & 15, lg = lane >> 4;

    const ushort_t* Qb = qkv + (long)w * NTOK * 576 + h * HD;
    const ushort_t* Kb = Qb + 192;
    const ushort_t* Vb = Qb + 384;

    bf16x8 zero8 = {0,0,0,0,0,0,0,0};

    bf16x8 qf[3], kf[3];
    #pragma unroll
    for (int t = 0; t < 3; ++t) {
        int row = t * 16 + lr;
        qf[t] = (row < NTOK) ? *(const bf16x8*)&Qb[(long)row * 576 + 8 * lg] : zero8;
        kf[t] = (row < NTOK) ? *(const bf16x8*)&Kb[(long)row * 576 + 8 * lg] : zero8;
    }
    f32x4 s[3][3] = {};
    #pragma unroll
    for (int mt = 0; mt < 3; ++mt)
        #pragma unroll
        for (int nt = 0; nt < 3; ++nt)
            s[mt][nt] = __builtin_amdgcn_mfma_f32_16x16x32_bf16(qf[mt], kf[nt], s[mt][nt], 0, 0, 0);

    const float* bb = bm + (((mlat * 2 + (mlon == MLON - 1)) * NH) + h) * (NTOK * NTOK);
    bool jv[3];
    #pragma unroll
    for (int nt = 0; nt < 3; ++nt) jv[nt] = (nt * 16 + lr) < NTOK;

    #pragma unroll
    for (int mt = 0; mt < 3; ++mt) {
        #pragma unroll
        for (int r = 0; r < 4; ++r) {
            int i = mt * 16 + lg * 4 + r;
            float v[3];
            #pragma unroll
            for (int nt = 0; nt < 3; ++nt) {
                int j = nt * 16 + lr;
                float t = s[mt][nt][r] * SCALE_F;
                if (i < NTOK && j < NTOK) t += bb[i * NTOK + j];
                v[nt] = t;
            }
            float mx = -1e30f;
            #pragma unroll
            for (int nt = 0; nt < 3; ++nt) if (jv[nt]) mx = fmaxf(mx, v[nt]);
            #pragma unroll
            for (int o = 1; o < 16; o <<= 1) mx = fmaxf(mx, __shfl_xor(mx, o, 64));
            float e[3], sum = 0.f;
            #pragma unroll
            for (int nt = 0; nt < 3; ++nt) { e[nt] = jv[nt] ? __expf(v[nt] - mx) : 0.f; sum += e[nt]; }
            #pragma unroll
            for (int o = 1; o < 16; o <<= 1) sum += __shfl_xor(sum, o, 64);
            float rs = 1.0f / sum;
            #pragma unroll
            for (int nt = 0; nt < 3; ++nt) s[mt][nt][r] = e[nt] * rs;
        }
    }

    #pragma unroll
    for (int mt = 0; mt < 3; ++mt)
        #pragma unroll
        for (int nt = 0; nt < 3; ++nt)
            #pragma unroll
            for (int r = 0; r < 4; ++r)
                Pls[wid][mt * 16 + lg * 4 + r][nt * 16 + lr] = f2b(s[mt][nt][r]);
    #pragma unroll
    for (int it = 0; it < 2; ++it) {
        int idx = it * 64 + lane;
        if (idx < 96) {
            int row = idx >> 1, hf = idx & 1;
            *(uint4*)&Pls[wid][row][48 + hf * 8] = uint4{0, 0, 0, 0};
        }
    }

    #pragma unroll
    for (int it = 0; it < 8; ++it) {
        int idx = it * 64 + lane;
        int row = idx >> 4, c = idx & 15;
        *(unsigned int*)&Vt[wid][row][36 + c * 2] = 0u;
    }
    #pragma unroll
    for (int it = 0; it < 9; ++it) {
        int e = it * 64 + lane;
        int tok = e >> 4, dp = e & 15;
        unsigned int v2 = *(const unsigned int*)&Vb[(long)tok * 576 + dp * 2];
        Vt[wid][dp * 2][tok]     = (ushort_t)(v2 & 0xffffu);
        Vt[wid][dp * 2 + 1][tok] = (ushort_t)(v2 >> 16);
    }

    f32x4 o[3][2] = {};
    #pragma unroll
    for (int kt = 0; kt < 2; ++kt) {
        bf16x8 pa[3], vb[2];
        #pragma unroll
        for (int mt = 0; mt < 3; ++mt)
            pa[mt] = *(const bf16x8*)&Pls[wid][mt * 16 + lr][kt * 32 + 8 * lg];
        #pragma unroll
        for (int nd = 0; nd < 2; ++nd)
            vb[nd] = *(const bf16x8*)&Vt[wid][nd * 16 + lr][kt * 32 + 8 * lg];
        #pragma unroll
        for (int mt = 0; mt < 3; ++mt)
            #pragma unroll
            for (int nd = 0; nd < 2; ++nd)
                o[mt][nd] = __builtin_amdgcn_mfma_f32_16x16x32_bf16(pa[mt], vb[nd], o[mt][nd], 0, 0, 0);
    }

    #pragma unroll
    for (int mt = 0; mt < 3; ++mt)
        #pragma unroll
        for (int nd = 0; nd < 2; ++nd)
            #pragma unroll
            for (int r = 0; r < 4; ++r) {
                int i = mt * 16 + lg * 4 + r;
                if (i < NTOK)
                    av[((long)w * NTOK + i) * CC + h * HD + nd * 16 + lr] = f2b(o[mt][nd][r]);
            }
}

// ---------------- launch ----------------
extern "C" void kernel_launch(void* const* d_in, const int* in_sizes, int n_in,
                              void* d_out, int out_size, void* d_ws, size_t ws_size,
                              hipStream_t stream) {
    const float* x        = (const float*)d_in[0];
    const float* n1w      = (const float*)d_in[1];
    const float* n1b      = (const float*)d_in[2];
    const float* qkv_w    = (const float*)d_in[3];
    const float* qkv_b    = (const float*)d_in[4];
    const float* proj_w   = (const float*)d_in[5];
    const float* proj_b   = (const float*)d_in[6];
    const float* btab     = (const float*)d_in[7];
    const float* n2w      = (const float*)d_in[8];
    const float* n2b      = (const float*)d_in[9];
    const float* fc1_w    = (const float*)d_in[10];
    const float* fc1_b    = (const float*)d_in[11];
    const float* fc2_w    = (const float*)d_in[12];
    const float* fc2_b    = (const float*)d_in[13];
    float* out = (float*)d_out;

    char* p = (char*)d_ws;
    ushort_t* xw  = (ushort_t*)p;  p += M_PAD * 192 * 2;
    ushort_t* big = (ushort_t*)p;  p += M_PAD * 768 * 2;
    ushort_t* av  = (ushort_t*)p;  p += M_PAD * 192 * 2;
    ushort_t* wqkv = (ushort_t*)p; p += 576 * 192 * 2;
    ushort_t* wproj= (ushort_t*)p; p += 192 * 192 * 2;
    ushort_t* wfc1 = (ushort_t*)p; p += 768 * 192 * 2;
    ushort_t* wfc2 = (ushort_t*)p; p += 192 * 768 * 2;
    float*    bmask= (float*)p;    p += MLAT * 2 * NH * NTOK * NTOK * 4;

    transpose_f2b<<<(576*192 + 255)/256, 256, 0, stream>>>(qkv_w, wqkv, 192, 576);
    transpose_f2b<<<(192*192 + 255)/256, 256, 0, stream>>>(proj_w, wproj, 192, 192);
    transpose_f2b<<<(768*192 + 255)/256, 256, 0, stream>>>(fc1_w, wfc1, 192, 768);
    transpose_f2b<<<(192*768 + 255)/256, 256, 0, stream>>>(fc2_w, wfc2, 768, 192);
    bias_mask_precompute<<<(MLAT*2*NH*NTOK*NTOK + 255)/256, 256, 0, stream>>>(btab, bmask);
    zero_bf16<<<(96*192 + 255)/256, 256, 0, stream>>>(av + M_TOK * 192, 96 * 192);

    ln1_window_kernel<<<M_PAD / 4, 256, 0, stream>>>(x, n1w, n1b, xw);

    // QKV: (M_PAD x 192) @ (192 x 576), 3 col-blocks
    gemm_bf16<0><<<507 * 3, 256, 0, stream>>>(
        xw, wqkv, qkv_b, big, nullptr, nullptr, 192, 576, M_PAD, 3, 507 * 3);

    attn_mfma_kernel<<<NWIN * NH / 4, 256, 0, stream>>>(big, bmask, av);

    // proj + window reverse + residual -> out (fp32), 1 col-block
    gemm_bf16<2><<<507, 256, 0, stream>>>(
        av, wproj, proj_b, nullptr, out, x, 192, 192, M_TOK, 1, 507);

    ln2_kernel<<<M_PAD / 4, 256, 0, stream>>>(out, n2w, n2b, xw);

    // FC1 + GELU: (M_PAD x 192) @ (192 x 768), 4 col-blocks
    gemm_bf16<1><<<507 * 4, 256, 0, stream>>>(
        xw, wfc1, fc1_b, big, nullptr, nullptr, 192, 768, M_PAD, 4, 507 * 4);

    // FC2 + residual accumulate into out, 1 col-block
    gemm_bf16<3><<<507, 256, 0, stream>>>(
        big, wfc2, fc2_b, nullptr, out, nullptr, 768, 192, M_TOK, 1, 507);
}